// Round 5
// baseline (821.897 us; speedup 1.0000x reference)
//
#include <hip/hip_runtime.h>
#include <math.h>

typedef float f32x4 __attribute__((ext_vector_type(4)));

// Problem constants (from reference)
#define N_NODES 100000
#define C_CL 30
#define D_IN 256

// d_out float offsets: (out, mincut, ortho, Z, S) concatenated
#define OUT_MAT 0        // 30*64
#define OUT_MC 1920
#define OUT_OR 1921
#define OUT_Z 1922       // 30*256
#define OUT_S 9602       // N*30

// ws float offsets
#define WS_M 0           // 30*256  (M = S^T x)      [written by k_reduce_b]
#define WS_SS 7680       // 30*30
#define WS_CS 8580       // 30 (colsum S)
#define WS_CUT 8610      // 1  (zeroed by k_prep, atomic from k_edges)
#define WS_H1 8640       // 30*256
#define WS_H2 16320      // 30*256
#define WS_WT4 24000     // 64*30 float4 = 7680 floats (W grouped by k4)
#define WS_S16 32000     // bf16 padded S: 1563*64 rows * 16 dwords
#define WS_Q 1632768     // stage-A partials: 16 * 8640 floats
#define Q_STRIDE 8640
#define WS_SLAB0 1771008 // per-block partial slabs start (floats)

// slab layout (floats, per block)
#define SLAB_SS 7680     // 4 w-partials * 900
#define SLAB_CS 11280    // 30
#define SLAB_STRIDE 11328
#define MAX_R 512

#define CHUNK 128
#define NCHUNK ((N_NODES + CHUNK - 1) / CHUNK)   // 782

// ---------------------------------------------------------------------------
// prep: build WT4[k4][c] = (W[4k4+0][c],...,W[4k4+3][c]); zero WS_CUT
__global__ __launch_bounds__(256)
void k_prep(const float* __restrict__ Wa, float* __restrict__ ws) {
  const int b = blockIdx.x, t = threadIdx.x;
  if (b < 8) {
    const int g = b * 256 + t;
    if (g < 64 * C_CL) {
      const int k4 = g / C_CL, c = g - C_CL * k4;
      float4 v;
      v.x = Wa[(4 * k4 + 0) * C_CL + c];
      v.y = Wa[(4 * k4 + 1) * C_CL + c];
      v.z = Wa[(4 * k4 + 2) * C_CL + c];
      v.w = Wa[(4 * k4 + 3) * C_CL + c];
      reinterpret_cast<float4*>(ws + WS_WT4)[g] = v;
    }
  } else {
    if (t == 0) ws[WS_CUT] = 0.f;
  }
}

// ---------------------------------------------------------------------------
// k_node v2: block = 128 threads = 2 waves over 64 nodes.
// wave khalf handles k in [khalf*128, khalf*128+128): 32 k4-steps in 4 phases
// of 8 with explicit double-buffered x loads (8 always in flight).
// W loads stay wave-uniform (scalar path). Combine + softmax via LDS.
__global__ __launch_bounds__(128, 3)
void k_node(const float* __restrict__ x, const float* __restrict__ wt4f,
            const float* __restrict__ ba, float* __restrict__ S_out,
            unsigned* __restrict__ S16) {
  __shared__ float st[64][33];
  const int t = threadIdx.x;
  const int lane = t & 63;
  const int khalf = t >> 6;              // wave-uniform
  const int node = blockIdx.x * 64 + lane;
  const bool valid = (node < N_NODES);
  const int node_c = valid ? node : (N_NODES - 1);   // clamp for addressing
  const f32x4* __restrict__ x4 = reinterpret_cast<const f32x4*>(x);
  const float4* __restrict__ wt4 = reinterpret_cast<const float4*>(wt4f);
  const f32x4* __restrict__ xr = x4 + (size_t)node_c * 64 + khalf * 32;

  float acc[C_CL];
  #pragma unroll
  for (int c = 0; c < C_CL; ++c) acc[c] = 0.f;

  f32x4 bufA[8], bufB[8];
  // prime: phase 0 loads
  #pragma unroll
  for (int i = 0; i < 8; ++i) bufA[i] = __builtin_nontemporal_load(&xr[i]);

  #pragma unroll
  for (int p = 0; p < 4; ++p) {
    // issue next phase's loads before consuming current
    if (p < 3) {
      if ((p & 1) == 0) {
        #pragma unroll
        for (int i = 0; i < 8; ++i)
          bufB[i] = __builtin_nontemporal_load(&xr[(p + 1) * 8 + i]);
      } else {
        #pragma unroll
        for (int i = 0; i < 8; ++i)
          bufA[i] = __builtin_nontemporal_load(&xr[(p + 1) * 8 + i]);
      }
    }
    #pragma unroll
    for (int i = 0; i < 8; ++i) {
      const f32x4 xv = ((p & 1) == 0) ? bufA[i] : bufB[i];
      const int k4 = khalf * 32 + p * 8 + i;
      #pragma unroll
      for (int c = 0; c < C_CL; ++c) {
        const float4 wv = wt4[k4 * C_CL + c];   // wave-uniform -> scalar loads
        acc[c] += xv.x * wv.x + xv.y * wv.y + xv.z * wv.z + xv.w * wv.w;
      }
    }
  }

  // ---- combine halves + softmax (wave0), via LDS ----
  if (khalf == 1) {
    #pragma unroll
    for (int c = 0; c < C_CL; ++c) st[lane][c] = acc[c];
  }
  __syncthreads();
  if (khalf == 0) {
    if (valid) {
      float mx = -3.0e38f;
      #pragma unroll
      for (int c = 0; c < C_CL; ++c) {
        acc[c] += st[lane][c] + ba[c];
        mx = fmaxf(mx, acc[c]);
      }
      float sm = 0.f;
      #pragma unroll
      for (int c = 0; c < C_CL; ++c) { acc[c] = __expf(acc[c] - mx); sm += acc[c]; }
      const float r = 1.f / sm;
      #pragma unroll
      for (int c = 0; c < C_CL; ++c) st[lane][c] = acc[c] * r;
    } else {
      #pragma unroll
      for (int c = 0; c < C_CL; ++c) st[lane][c] = 0.f;
    }
    st[lane][30] = 0.f; st[lane][31] = 0.f;
  }
  __syncthreads();

  // ---- outputs (128 threads) ----
  // packed fp32 S: 64 rows * 30 floats = 1920 = 15 * 128
  const int gbase = blockIdx.x * 1920;
  #pragma unroll
  for (int i = 0; i < 15; ++i) {
    const unsigned idx = i * 128 + t;
    const unsigned n = idx / 30u, c = idx - 30u * n;
    const int g = gbase + (int)idx;
    if (g < N_NODES * C_CL) S_out[g] = st[n][c];
  }
  // bf16 padded S: 64 rows * 16 dwords = 1024 = 8 * 128
  const unsigned sbase = blockIdx.x * 1024;
  #pragma unroll
  for (int i = 0; i < 8; ++i) {
    const unsigned idx = i * 128 + t;
    const unsigned n = idx >> 4, j = idx & 15;
    const unsigned lo = __float_as_uint(st[n][j * 2]);
    const unsigned hi = __float_as_uint(st[n][j * 2 + 1]);
    const unsigned lo16 = (lo + 0x7fffu + ((lo >> 16) & 1u)) >> 16;
    const unsigned hi16 = (hi + 0x7fffu + ((hi >> 16) & 1u)) >> 16;
    S16[sbase + idx] = lo16 | (hi16 << 16);
  }
}

// ---------------------------------------------------------------------------
// M = S^T x (+ SS = S^T S, colsum). Grid-stride over 128-node chunks,
// persistent register accumulators, per-block slab output (no atomics).
__global__ __launch_bounds__(256, 2)
void k_M2(const float* __restrict__ x, const float* __restrict__ Sp,
          float* __restrict__ slabs, const int R) {
  __shared__ float sraw[8192];                 // 32 KB, dual-use
  float (*sm)[32] = reinterpret_cast<float (*)[32]>(sraw);
  const int t = threadIdx.x;
  const int h = t >> 7, sub = (t >> 6) & 1, lc = t & 63;  // M layout
  const int i4 = (t >> 3) & 7, j4 = t & 7, w = t >> 6;    // SS layout
  const f32x4* __restrict__ x4 = reinterpret_cast<const f32x4*>(x);

  float a[16][4];
  #pragma unroll
  for (int j = 0; j < 16; ++j) { a[j][0] = 0.f; a[j][1] = 0.f; a[j][2] = 0.f; a[j][3] = 0.f; }
  float ssq[16];
  #pragma unroll
  for (int j = 0; j < 16; ++j) ssq[j] = 0.f;
  float cs = 0.f;

  for (int chunk = blockIdx.x; chunk < NCHUNK; chunk += R) {
    const int node0 = chunk * CHUNK;
    const int rows_valid = N_NODES - node0;
    __syncthreads();
    #pragma unroll
    for (int i = 0; i < 15; ++i) {
      const int idx = i * 256 + t;
      const int n = idx / 30, c = idx - 30 * n;
      const int g = node0 * C_CL + idx;
      sm[n][c] = (g < N_NODES * C_CL) ? Sp[g] : 0.f;
    }
    sm[t & 127][30 + (t >> 7)] = 0.f;
    __syncthreads();

    if (rows_valid >= CHUNK) {
      #pragma unroll 4
      for (int n = 0; n < 64; ++n) {
        const int nn = sub * 64 + n;
        const f32x4 xv = __builtin_nontemporal_load(&x4[(size_t)(node0 + nn) * 64 + lc]);
        const float4 s0 = *reinterpret_cast<const float4*>(&sm[nn][h * 16 + 0]);
        const float4 s1 = *reinterpret_cast<const float4*>(&sm[nn][h * 16 + 4]);
        const float4 s2 = *reinterpret_cast<const float4*>(&sm[nn][h * 16 + 8]);
        const float4 s3 = *reinterpret_cast<const float4*>(&sm[nn][h * 16 + 12]);
        const float sv[16] = {s0.x, s0.y, s0.z, s0.w, s1.x, s1.y, s1.z, s1.w,
                              s2.x, s2.y, s2.z, s2.w, s3.x, s3.y, s3.z, s3.w};
        #pragma unroll
        for (int j = 0; j < 16; ++j) {
          a[j][0] += sv[j] * xv.x; a[j][1] += sv[j] * xv.y;
          a[j][2] += sv[j] * xv.z; a[j][3] += sv[j] * xv.w;
        }
      }
    } else {
      for (int n = 0; n < 64; ++n) {
        const int nn = sub * 64 + n;
        f32x4 xv = (f32x4)0.f;
        if (nn < rows_valid) xv = x4[(size_t)(node0 + nn) * 64 + lc];
        const float4 s0 = *reinterpret_cast<const float4*>(&sm[nn][h * 16 + 0]);
        const float4 s1 = *reinterpret_cast<const float4*>(&sm[nn][h * 16 + 4]);
        const float4 s2 = *reinterpret_cast<const float4*>(&sm[nn][h * 16 + 8]);
        const float4 s3 = *reinterpret_cast<const float4*>(&sm[nn][h * 16 + 12]);
        const float sv[16] = {s0.x, s0.y, s0.z, s0.w, s1.x, s1.y, s1.z, s1.w,
                              s2.x, s2.y, s2.z, s2.w, s3.x, s3.y, s3.z, s3.w};
        #pragma unroll
        for (int j = 0; j < 16; ++j) {
          a[j][0] += sv[j] * xv.x; a[j][1] += sv[j] * xv.y;
          a[j][2] += sv[j] * xv.z; a[j][3] += sv[j] * xv.w;
        }
      }
    }

    #pragma unroll 4
    for (int n = 0; n < 32; ++n) {
      const int nn = w * 32 + n;
      const float4 av = *reinterpret_cast<const float4*>(&sm[nn][i4 * 4]);
      const float4 bv = *reinterpret_cast<const float4*>(&sm[nn][j4 * 4]);
      const float af[4] = {av.x, av.y, av.z, av.w};
      const float bf[4] = {bv.x, bv.y, bv.z, bv.w};
      #pragma unroll
      for (int ii = 0; ii < 4; ++ii)
        #pragma unroll
        for (int jj = 0; jj < 4; ++jj) ssq[ii * 4 + jj] += af[ii] * bf[jj];
    }
    if (t < C_CL) {
      #pragma unroll 4
      for (int n = 0; n < CHUNK; ++n) cs += sm[n][t];
    }
  }

  // ---- flush to private slab (plain stores; zero contention) ----
  float* __restrict__ slab = slabs + (size_t)blockIdx.x * SLAB_STRIDE;
  __syncthreads();
  if (sub == 1) {
    #pragma unroll
    for (int j = 0; j < 16; ++j) {
      const int c = h * 16 + j;
      if (c < C_CL) {
        #pragma unroll
        for (int q = 0; q < 4; ++q) sraw[c * 256 + lc * 4 + q] = a[j][q];
      }
    }
  }
  __syncthreads();
  if (sub == 0) {
    #pragma unroll
    for (int j = 0; j < 16; ++j) {
      const int c = h * 16 + j;
      if (c < C_CL) {
        #pragma unroll
        for (int q = 0; q < 4; ++q)
          slab[c * 256 + lc * 4 + q] = a[j][q] + sraw[c * 256 + lc * 4 + q];
      }
    }
  }
  #pragma unroll
  for (int ii = 0; ii < 4; ++ii) {
    #pragma unroll
    for (int jj = 0; jj < 4; ++jj) {
      const int gi = i4 * 4 + ii, gj = j4 * 4 + jj;
      if (gi < C_CL && gj < C_CL)
        slab[SLAB_SS + w * 900 + gi * C_CL + gj] = ssq[ii * 4 + jj];
    }
  }
  if (t < C_CL) slab[SLAB_CS + t] = cs;
}

// ---------------------------------------------------------------------------
// Stage A: 34 x 16 blocks; group g sums its ~R/16 slabs with batched loads.
__global__ __launch_bounds__(256)
void k_reduce_a(const float* __restrict__ slabs, const int R,
                float* __restrict__ Q) {
  const int i = blockIdx.x * 256 + threadIdx.x;
  const int g = blockIdx.y;
  if (i >= 8610) return;
  const int per = (R + 15) >> 4;
  const int r0 = g * per;
  const int r1 = min(r0 + per, R);
  size_t off;
  bool is_ss = false;
  if (i < 7680) off = (size_t)i;
  else if (i < 8580) { off = SLAB_SS + (i - 7680); is_ss = true; }
  else off = SLAB_CS + (i - 8580);

  float s = 0.f;
  if (!is_ss) {
    int r = r0;
    for (; r + 8 <= r1; r += 8) {
      const float* p = slabs + (size_t)r * SLAB_STRIDE + off;
      const float v0 = p[0];
      const float v1 = p[1 * SLAB_STRIDE];
      const float v2 = p[2 * SLAB_STRIDE];
      const float v3 = p[3 * SLAB_STRIDE];
      const float v4 = p[4 * SLAB_STRIDE];
      const float v5 = p[5 * SLAB_STRIDE];
      const float v6 = p[6 * SLAB_STRIDE];
      const float v7 = p[7 * SLAB_STRIDE];
      s += ((v0 + v1) + (v2 + v3)) + ((v4 + v5) + (v6 + v7));
    }
    for (; r < r1; ++r) s += slabs[(size_t)r * SLAB_STRIDE + off];
  } else {
    int r = r0;
    for (; r + 2 <= r1; r += 2) {
      const float* p0 = slabs + (size_t)r * SLAB_STRIDE + off;
      const float* p1 = p0 + SLAB_STRIDE;
      s += ((p0[0] + p0[900]) + (p0[1800] + p0[2700]))
         + ((p1[0] + p1[900]) + (p1[1800] + p1[2700]));
    }
    if (r < r1) {
      const float* p = slabs + (size_t)r * SLAB_STRIDE + off;
      s += (p[0] + p[900]) + (p[1800] + p[2700]);
    }
  }
  Q[(size_t)g * Q_STRIDE + i] = s;
}

// Stage B: ws[i] = sum_g Q[g][i], 16 unrolled independent loads.
__global__ __launch_bounds__(256)
void k_reduce_b(const float* __restrict__ Q, float* __restrict__ ws) {
  const int i = blockIdx.x * 256 + threadIdx.x;
  if (i >= 8610) return;
  float s = 0.f;
  #pragma unroll
  for (int g = 0; g < 16; ++g) s += Q[(size_t)g * Q_STRIDE + i];
  ws[i] = s;
}

// ---------------------------------------------------------------------------
// cut = sum_e dot(S[r], S[c]); bf16 rows (one 64B line), wave-cooperative,
// index loads software-pipelined one iteration ahead.
__device__ __forceinline__ float blo(unsigned u) { return __uint_as_float(u << 16); }
__device__ __forceinline__ float bhi(unsigned u) { return __uint_as_float(u & 0xffff0000u); }

__global__ __launch_bounds__(256)
void k_edges(const int* __restrict__ ei, const int E,
             const unsigned* __restrict__ S16, float* __restrict__ ws) {
  const int t = threadIdx.x;
  const int lane = t & 63;
  const int el = lane >> 2, part = lane & 3;
  const int gw = (blockIdx.x * 256 + t) >> 6;
  const int nw = gridDim.x * 4;
  const int step = nw * 16;
  const int* __restrict__ row = ei;
  const int* __restrict__ col = ei + E;
  float acc = 0.f;

  int base = gw * 16;
  int e = base + el;
  int r = 0, c = 0;
  if (e < E) { r = row[e]; c = col[e]; }
  for (; base < E; ) {
    const bool valid = (e < E);
    uint4 ur = make_uint4(0, 0, 0, 0), uc = make_uint4(0, 0, 0, 0);
    if (valid) {
      ur = *reinterpret_cast<const uint4*>(S16 + (size_t)r * 16 + part * 4);
      uc = *reinterpret_cast<const uint4*>(S16 + (size_t)c * 16 + part * 4);
    }
    // prefetch next indices while gathers are in flight
    const int nb = base + step;
    const int en = nb + el;
    int rn = 0, cn = 0;
    if (en < E) { rn = row[en]; cn = col[en]; }
    float d = 0.f;
    if (valid) {
      d  = blo(ur.x) * blo(uc.x) + bhi(ur.x) * bhi(uc.x);
      d += blo(ur.y) * blo(uc.y) + bhi(ur.y) * bhi(uc.y);
      d += blo(ur.z) * blo(uc.z) + bhi(ur.z) * bhi(uc.z);
      d += blo(ur.w) * blo(uc.w) + bhi(ur.w) * bhi(uc.w);
    }
    d += __shfl_xor(d, 1, 64);
    d += __shfl_xor(d, 2, 64);
    acc += d;
    base = nb; e = en; r = rn; c = cn;
  }
  #pragma unroll
  for (int m = 4; m < 64; m <<= 1) acc += __shfl_xor(acc, m, 64);
  __shared__ float wsum[4];
  if (lane == 0) wsum[t >> 6] = acc;
  __syncthreads();
  if (t == 0)
    atomicAdd(&ws[WS_CUT], wsum[0] + wsum[1] + wsum[2] + wsum[3]);
}

// ---------------------------------------------------------------------------
// Z = M @ W_proj + colsum(S) (x) b_proj
__global__ __launch_bounds__(256)
void k_z(const float* __restrict__ ws, const float* __restrict__ Wp,
         const float* __restrict__ bp, float* __restrict__ out) {
  const int r = blockIdx.x, t = threadIdx.x;
  const float* m = ws + WS_M + r * 256;
  float acc = ws[WS_CS + r] * bp[t];
  #pragma unroll 8
  for (int k = 0; k < 256; ++k) acc += m[k] * Wp[(size_t)k * 256 + t];
  out[OUT_Z + r * 256 + t] = acc;
}

// ---------------------------------------------------------------------------
// Shapley layer (mask=ones, n=30): h = relu((in + colsum(in)/30) @ W)
__global__ __launch_bounds__(256)
void k_shlayer(const float* __restrict__ in, const float* __restrict__ W,
               float* __restrict__ outp) {
  __shared__ float sh[256];
  const int r = blockIdx.x, t = threadIdx.x;
  float cs = 0.f;
  #pragma unroll
  for (int i = 0; i < C_CL; ++i) cs += in[i * 256 + t];
  sh[t] = in[r * 256 + t] + (1.f / 30.f) * cs;
  __syncthreads();
  float acc = 0.f;
  #pragma unroll 8
  for (int k = 0; k < 256; ++k) acc += sh[k] * W[(size_t)k * 256 + t];
  outp[r * 256 + t] = fmaxf(acc, 0.f);
}

// ---------------------------------------------------------------------------
// out = h2 @ W_out + b_out ; block 30: mincut + ortho scalars
__global__ __launch_bounds__(64)
void k_out(const float* __restrict__ ws, const float* __restrict__ Wo,
           const float* __restrict__ bo, float* __restrict__ out,
           const float vol) {
  const int r = blockIdx.x, t = threadIdx.x;
  if (r < C_CL) {
    const float* hrow = ws + WS_H2 + r * 256;
    float acc = bo[t];
    #pragma unroll 8
    for (int k = 0; k < 256; ++k) acc += hrow[k] * Wo[k * 64 + t];
    out[OUT_MAT + r * 64 + t] = acc;
  } else {
    float s = 0.f;
    for (int i = t; i < C_CL * C_CL; i += 64) {
      const float d = ws[WS_SS + i] - ((i / C_CL == i % C_CL) ? 1.f : 0.f);
      s += d * d;
    }
    #pragma unroll
    for (int m = 32; m >= 1; m >>= 1) s += __shfl_xor(s, m, 64);
    if (t == 0) {
      out[OUT_OR] = sqrtf(s);
      out[OUT_MC] = -ws[WS_CUT] / (vol + 1e-9f);
    }
  }
}

// ---------------------------------------------------------------------------
extern "C" void kernel_launch(void* const* d_in, const int* in_sizes, int n_in,
                              void* d_out, int out_size, void* d_ws, size_t ws_size,
                              hipStream_t stream) {
  (void)n_in; (void)out_size;
  const float* x  = (const float*)d_in[0];
  const int*   ei = (const int*)d_in[1];
  const float* Wa = (const float*)d_in[2];
  const float* ba = (const float*)d_in[3];
  const float* Wp = (const float*)d_in[4];
  const float* bp = (const float*)d_in[5];
  const float* W1 = (const float*)d_in[6];
  const float* W2 = (const float*)d_in[7];
  const float* Wo = (const float*)d_in[8];
  const float* bo = (const float*)d_in[9];
  float* out = (float*)d_out;
  float* ws  = (float*)d_ws;
  unsigned* S16 = (unsigned*)(ws + WS_S16);
  float* Q = ws + WS_Q;
  float* slabs = ws + WS_SLAB0;
  const int E = in_sizes[1] / 2;

  long avail = (long)(ws_size / 4) - WS_SLAB0;
  int R = (int)(avail / SLAB_STRIDE);
  if (R > MAX_R) R = MAX_R;
  if (R < 1) R = 1;

  k_prep<<<9, 256, 0, stream>>>(Wa, ws);
  k_node<<<1563, 128, 0, stream>>>(x, ws + WS_WT4, ba, out + OUT_S, S16);
  k_M2<<<R, 256, 0, stream>>>(x, out + OUT_S, slabs, R);
  k_reduce_a<<<dim3(34, 16), 256, 0, stream>>>(slabs, R, Q);
  k_reduce_b<<<34, 256, 0, stream>>>(Q, ws);
  k_edges<<<2048, 256, 0, stream>>>(ei, E, S16, ws);
  k_z<<<C_CL, 256, 0, stream>>>(ws, Wp, bp, out);
  k_shlayer<<<C_CL, 256, 0, stream>>>(out + OUT_Z, W1, ws + WS_H1);
  k_shlayer<<<C_CL, 256, 0, stream>>>(ws + WS_H1, W2, ws + WS_H2);
  k_out<<<C_CL + 1, 64, 0, stream>>>(ws, Wo, bo, out, (float)E);
}

// Round 6
// 440.683 us; speedup vs baseline: 1.8651x; 1.8651x over previous
//
#include <hip/hip_runtime.h>
#include <math.h>

typedef float f32x4 __attribute__((ext_vector_type(4)));

// Problem constants (from reference)
#define N_NODES 100000
#define C_CL 30
#define D_IN 256

// d_out float offsets: (out, mincut, ortho, Z, S) concatenated
#define OUT_MAT 0        // 30*64
#define OUT_MC 1920
#define OUT_OR 1921
#define OUT_Z 1922       // 30*256
#define OUT_S 9602       // N*30

// ws float offsets
#define WS_M 0           // 30*256  (M = S^T x)      [written by k_reduce_b]
#define WS_SS 7680       // 30*30
#define WS_CS 8580       // 30 (colsum S)
#define WS_CUT 8610      // 1  (zeroed by k_prep, atomic from k_edges)
#define WS_H1 8640       // 30*256
#define WS_H2 16320      // 30*256
#define WS_WT4 24000     // 64*32 float4 = 8192 floats (W padded to 32 cols)
#define WS_S16 32256     // bf16 padded S: 1563*64 rows * 16 dwords (ends 1632768)
#define WS_Q 1632768     // stage-A partials: 16 * 8640 floats
#define Q_STRIDE 8640
#define WS_SLAB0 1771008 // per-block partial slabs start (floats)

// slab layout (floats, per block)
#define SLAB_SS 7680     // 4 w-partials * 900
#define SLAB_CS 11280    // 30
#define SLAB_STRIDE 11328
#define MAX_R 512

#define CHUNK 128
#define NCHUNK ((N_NODES + CHUNK - 1) / CHUNK)   // 782

// ---------------------------------------------------------------------------
// prep: build WT4p[k4][c] (c padded to 32, cols 30/31 = 0); zero WS_CUT
__global__ __launch_bounds__(256)
void k_prep(const float* __restrict__ Wa, float* __restrict__ ws) {
  const int b = blockIdx.x, t = threadIdx.x;
  if (b < 8) {
    const int g = b * 256 + t;          // 0..2047 = 64 k4 * 32 c
    const int k4 = g >> 5, c = g & 31;
    float4 v = make_float4(0.f, 0.f, 0.f, 0.f);
    if (c < C_CL) {
      v.x = Wa[(4 * k4 + 0) * C_CL + c];
      v.y = Wa[(4 * k4 + 1) * C_CL + c];
      v.z = Wa[(4 * k4 + 2) * C_CL + c];
      v.w = Wa[(4 * k4 + 3) * C_CL + c];
    }
    reinterpret_cast<float4*>(ws + WS_WT4)[g] = v;
  } else {
    if (t == 0) ws[WS_CUT] = 0.f;
  }
}

// ---------------------------------------------------------------------------
// k_node v3: block = 256 threads = 4 waves over the SAME 64 nodes.
// Wave cg computes clusters [cg*8, cg*8+8) only: acc[8] keeps VGPRs low
// (round-5 spill storm: acc[30]+16xf32x4 bufs -> 521 MB scratch WRITE).
// All 4 waves read the same x lines (plain loads -> L1/L2 dedup).
// W loads wave-uniform via readfirstlane -> scalar path. Softmax via LDS.
__global__ __launch_bounds__(256, 4)
void k_node(const float* __restrict__ x, const float* __restrict__ wt4f,
            const float* __restrict__ ba, float* __restrict__ S_out,
            unsigned* __restrict__ S16) {
  __shared__ float lg[64][33];
  const int t = threadIdx.x;
  const int lane = t & 63;
  const int cg = __builtin_amdgcn_readfirstlane(t >> 6);   // wave-uniform 0..3
  const int node = blockIdx.x * 64 + lane;
  const bool valid = (node < N_NODES);
  const int node_c = valid ? node : (N_NODES - 1);
  const f32x4* __restrict__ xr =
      reinterpret_cast<const f32x4*>(x) + (size_t)node_c * 64;
  const float4* __restrict__ wt4 = reinterpret_cast<const float4*>(wt4f);

  float acc[8];
  #pragma unroll
  for (int j = 0; j < 8; ++j) acc[j] = 0.f;

  #pragma unroll 8
  for (int k4 = 0; k4 < 64; ++k4) {
    const f32x4 xv = xr[k4];                       // cached: shared by 4 waves
    #pragma unroll
    for (int j = 0; j < 8; ++j) {
      const float4 wv = wt4[k4 * 32 + cg * 8 + j]; // scalar loads
      acc[j] += xv.x * wv.x + xv.y * wv.y + xv.z * wv.z + xv.w * wv.w;
    }
  }
  #pragma unroll
  for (int j = 0; j < 8; ++j) lg[lane][cg * 8 + j] = acc[j];
  __syncthreads();

  // ---- softmax by wave 0 (reads combined logits from LDS) ----
  if (t < 64) {
    if (valid) {
      float v[C_CL];
      float mx = -3.0e38f;
      #pragma unroll
      for (int c = 0; c < C_CL; ++c) {
        v[c] = lg[t][c] + ba[c];
        mx = fmaxf(mx, v[c]);
      }
      float sm = 0.f;
      #pragma unroll
      for (int c = 0; c < C_CL; ++c) { v[c] = __expf(v[c] - mx); sm += v[c]; }
      const float r = 1.f / sm;
      #pragma unroll
      for (int c = 0; c < C_CL; ++c) lg[t][c] = v[c] * r;
    } else {
      #pragma unroll
      for (int c = 0; c < C_CL; ++c) lg[t][c] = 0.f;
    }
    lg[t][30] = 0.f; lg[t][31] = 0.f;
  }
  __syncthreads();

  // ---- outputs (256 threads) ----
  // packed fp32 S: 64 rows * 30 floats = 1920
  const int gbase = blockIdx.x * 1920;
  #pragma unroll
  for (int i = 0; i < 8; ++i) {
    const unsigned idx = i * 256 + t;
    if (idx < 1920u) {
      const unsigned n = idx / 30u, c = idx - 30u * n;
      const int g = gbase + (int)idx;
      if (g < N_NODES * C_CL) S_out[g] = lg[n][c];
    }
  }
  // bf16 padded S: 64 rows * 16 dwords = 1024
  const unsigned sbase = blockIdx.x * 1024;
  #pragma unroll
  for (int i = 0; i < 4; ++i) {
    const unsigned idx = i * 256 + t;
    const unsigned n = idx >> 4, j = idx & 15;
    const unsigned lo = __float_as_uint(lg[n][j * 2]);
    const unsigned hi = __float_as_uint(lg[n][j * 2 + 1]);
    const unsigned lo16 = (lo + 0x7fffu + ((lo >> 16) & 1u)) >> 16;
    const unsigned hi16 = (hi + 0x7fffu + ((hi >> 16) & 1u)) >> 16;
    S16[sbase + idx] = lo16 | (hi16 << 16);
  }
}

// ---------------------------------------------------------------------------
// M = S^T x (+ SS = S^T S, colsum). Grid-stride over 128-node chunks,
// persistent register accumulators, per-block slab output (no atomics).
__global__ __launch_bounds__(256, 2)
void k_M2(const float* __restrict__ x, const float* __restrict__ Sp,
          float* __restrict__ slabs, const int R) {
  __shared__ float sraw[8192];                 // 32 KB, dual-use
  float (*sm)[32] = reinterpret_cast<float (*)[32]>(sraw);
  const int t = threadIdx.x;
  const int h = t >> 7, sub = (t >> 6) & 1, lc = t & 63;  // M layout
  const int i4 = (t >> 3) & 7, j4 = t & 7, w = t >> 6;    // SS layout
  const f32x4* __restrict__ x4 = reinterpret_cast<const f32x4*>(x);

  float a[16][4];
  #pragma unroll
  for (int j = 0; j < 16; ++j) { a[j][0] = 0.f; a[j][1] = 0.f; a[j][2] = 0.f; a[j][3] = 0.f; }
  float ssq[16];
  #pragma unroll
  for (int j = 0; j < 16; ++j) ssq[j] = 0.f;
  float cs = 0.f;

  for (int chunk = blockIdx.x; chunk < NCHUNK; chunk += R) {
    const int node0 = chunk * CHUNK;
    const int rows_valid = N_NODES - node0;
    __syncthreads();
    #pragma unroll
    for (int i = 0; i < 15; ++i) {
      const int idx = i * 256 + t;
      const int n = idx / 30, c = idx - 30 * n;
      const int g = node0 * C_CL + idx;
      sm[n][c] = (g < N_NODES * C_CL) ? Sp[g] : 0.f;
    }
    sm[t & 127][30 + (t >> 7)] = 0.f;
    __syncthreads();

    if (rows_valid >= CHUNK) {
      #pragma unroll 4
      for (int n = 0; n < 64; ++n) {
        const int nn = sub * 64 + n;
        const f32x4 xv = __builtin_nontemporal_load(&x4[(size_t)(node0 + nn) * 64 + lc]);
        const float4 s0 = *reinterpret_cast<const float4*>(&sm[nn][h * 16 + 0]);
        const float4 s1 = *reinterpret_cast<const float4*>(&sm[nn][h * 16 + 4]);
        const float4 s2 = *reinterpret_cast<const float4*>(&sm[nn][h * 16 + 8]);
        const float4 s3 = *reinterpret_cast<const float4*>(&sm[nn][h * 16 + 12]);
        const float sv[16] = {s0.x, s0.y, s0.z, s0.w, s1.x, s1.y, s1.z, s1.w,
                              s2.x, s2.y, s2.z, s2.w, s3.x, s3.y, s3.z, s3.w};
        #pragma unroll
        for (int j = 0; j < 16; ++j) {
          a[j][0] += sv[j] * xv.x; a[j][1] += sv[j] * xv.y;
          a[j][2] += sv[j] * xv.z; a[j][3] += sv[j] * xv.w;
        }
      }
    } else {
      for (int n = 0; n < 64; ++n) {
        const int nn = sub * 64 + n;
        f32x4 xv = (f32x4)0.f;
        if (nn < rows_valid) xv = x4[(size_t)(node0 + nn) * 64 + lc];
        const float4 s0 = *reinterpret_cast<const float4*>(&sm[nn][h * 16 + 0]);
        const float4 s1 = *reinterpret_cast<const float4*>(&sm[nn][h * 16 + 4]);
        const float4 s2 = *reinterpret_cast<const float4*>(&sm[nn][h * 16 + 8]);
        const float4 s3 = *reinterpret_cast<const float4*>(&sm[nn][h * 16 + 12]);
        const float sv[16] = {s0.x, s0.y, s0.z, s0.w, s1.x, s1.y, s1.z, s1.w,
                              s2.x, s2.y, s2.z, s2.w, s3.x, s3.y, s3.z, s3.w};
        #pragma unroll
        for (int j = 0; j < 16; ++j) {
          a[j][0] += sv[j] * xv.x; a[j][1] += sv[j] * xv.y;
          a[j][2] += sv[j] * xv.z; a[j][3] += sv[j] * xv.w;
        }
      }
    }

    #pragma unroll 4
    for (int n = 0; n < 32; ++n) {
      const int nn = w * 32 + n;
      const float4 av = *reinterpret_cast<const float4*>(&sm[nn][i4 * 4]);
      const float4 bv = *reinterpret_cast<const float4*>(&sm[nn][j4 * 4]);
      const float af[4] = {av.x, av.y, av.z, av.w};
      const float bf[4] = {bv.x, bv.y, bv.z, bv.w};
      #pragma unroll
      for (int ii = 0; ii < 4; ++ii)
        #pragma unroll
        for (int jj = 0; jj < 4; ++jj) ssq[ii * 4 + jj] += af[ii] * bf[jj];
    }
    if (t < C_CL) {
      #pragma unroll 4
      for (int n = 0; n < CHUNK; ++n) cs += sm[n][t];
    }
  }

  // ---- flush to private slab (plain stores; zero contention) ----
  float* __restrict__ slab = slabs + (size_t)blockIdx.x * SLAB_STRIDE;
  __syncthreads();
  if (sub == 1) {
    #pragma unroll
    for (int j = 0; j < 16; ++j) {
      const int c = h * 16 + j;
      if (c < C_CL) {
        #pragma unroll
        for (int q = 0; q < 4; ++q) sraw[c * 256 + lc * 4 + q] = a[j][q];
      }
    }
  }
  __syncthreads();
  if (sub == 0) {
    #pragma unroll
    for (int j = 0; j < 16; ++j) {
      const int c = h * 16 + j;
      if (c < C_CL) {
        #pragma unroll
        for (int q = 0; q < 4; ++q)
          slab[c * 256 + lc * 4 + q] = a[j][q] + sraw[c * 256 + lc * 4 + q];
      }
    }
  }
  #pragma unroll
  for (int ii = 0; ii < 4; ++ii) {
    #pragma unroll
    for (int jj = 0; jj < 4; ++jj) {
      const int gi = i4 * 4 + ii, gj = j4 * 4 + jj;
      if (gi < C_CL && gj < C_CL)
        slab[SLAB_SS + w * 900 + gi * C_CL + gj] = ssq[ii * 4 + jj];
    }
  }
  if (t < C_CL) slab[SLAB_CS + t] = cs;
}

// ---------------------------------------------------------------------------
// Stage A: 34 x 16 blocks; group g sums its ~R/16 slabs with batched loads.
__global__ __launch_bounds__(256)
void k_reduce_a(const float* __restrict__ slabs, const int R,
                float* __restrict__ Q) {
  const int i = blockIdx.x * 256 + threadIdx.x;
  const int g = blockIdx.y;
  if (i >= 8610) return;
  const int per = (R + 15) >> 4;
  const int r0 = g * per;
  const int r1 = min(r0 + per, R);
  size_t off;
  bool is_ss = false;
  if (i < 7680) off = (size_t)i;
  else if (i < 8580) { off = SLAB_SS + (i - 7680); is_ss = true; }
  else off = SLAB_CS + (i - 8580);

  float s = 0.f;
  if (!is_ss) {
    int r = r0;
    for (; r + 8 <= r1; r += 8) {
      const float* p = slabs + (size_t)r * SLAB_STRIDE + off;
      const float v0 = p[0];
      const float v1 = p[1 * SLAB_STRIDE];
      const float v2 = p[2 * SLAB_STRIDE];
      const float v3 = p[3 * SLAB_STRIDE];
      const float v4 = p[4 * SLAB_STRIDE];
      const float v5 = p[5 * SLAB_STRIDE];
      const float v6 = p[6 * SLAB_STRIDE];
      const float v7 = p[7 * SLAB_STRIDE];
      s += ((v0 + v1) + (v2 + v3)) + ((v4 + v5) + (v6 + v7));
    }
    for (; r < r1; ++r) s += slabs[(size_t)r * SLAB_STRIDE + off];
  } else {
    int r = r0;
    for (; r + 2 <= r1; r += 2) {
      const float* p0 = slabs + (size_t)r * SLAB_STRIDE + off;
      const float* p1 = p0 + SLAB_STRIDE;
      s += ((p0[0] + p0[900]) + (p0[1800] + p0[2700]))
         + ((p1[0] + p1[900]) + (p1[1800] + p1[2700]));
    }
    if (r < r1) {
      const float* p = slabs + (size_t)r * SLAB_STRIDE + off;
      s += (p[0] + p[900]) + (p[1800] + p[2700]);
    }
  }
  Q[(size_t)g * Q_STRIDE + i] = s;
}

// Stage B: ws[i] = sum_g Q[g][i], 16 unrolled independent loads.
__global__ __launch_bounds__(256)
void k_reduce_b(const float* __restrict__ Q, float* __restrict__ ws) {
  const int i = blockIdx.x * 256 + threadIdx.x;
  if (i >= 8610) return;
  float s = 0.f;
  #pragma unroll
  for (int g = 0; g < 16; ++g) s += Q[(size_t)g * Q_STRIDE + i];
  ws[i] = s;
}

// ---------------------------------------------------------------------------
// cut = sum_e dot(S[r], S[c]); bf16 rows (one 64B line), wave-cooperative,
// index loads software-pipelined one iteration ahead.
__device__ __forceinline__ float blo(unsigned u) { return __uint_as_float(u << 16); }
__device__ __forceinline__ float bhi(unsigned u) { return __uint_as_float(u & 0xffff0000u); }

__global__ __launch_bounds__(256)
void k_edges(const int* __restrict__ ei, const int E,
             const unsigned* __restrict__ S16, float* __restrict__ ws) {
  const int t = threadIdx.x;
  const int lane = t & 63;
  const int el = lane >> 2, part = lane & 3;
  const int gw = (blockIdx.x * 256 + t) >> 6;
  const int nw = gridDim.x * 4;
  const int step = nw * 16;
  const int* __restrict__ row = ei;
  const int* __restrict__ col = ei + E;
  float acc = 0.f;

  int base = gw * 16;
  int e = base + el;
  int r = 0, c = 0;
  if (e < E) { r = row[e]; c = col[e]; }
  for (; base < E; ) {
    const bool valid = (e < E);
    uint4 ur = make_uint4(0, 0, 0, 0), uc = make_uint4(0, 0, 0, 0);
    if (valid) {
      ur = *reinterpret_cast<const uint4*>(S16 + (size_t)r * 16 + part * 4);
      uc = *reinterpret_cast<const uint4*>(S16 + (size_t)c * 16 + part * 4);
    }
    // prefetch next indices while gathers are in flight
    const int nb = base + step;
    const int en = nb + el;
    int rn = 0, cn = 0;
    if (en < E) { rn = row[en]; cn = col[en]; }
    float d = 0.f;
    if (valid) {
      d  = blo(ur.x) * blo(uc.x) + bhi(ur.x) * bhi(uc.x);
      d += blo(ur.y) * blo(uc.y) + bhi(ur.y) * bhi(uc.y);
      d += blo(ur.z) * blo(uc.z) + bhi(ur.z) * bhi(uc.z);
      d += blo(ur.w) * blo(uc.w) + bhi(ur.w) * bhi(uc.w);
    }
    d += __shfl_xor(d, 1, 64);
    d += __shfl_xor(d, 2, 64);
    acc += d;
    base = nb; e = en; r = rn; c = cn;
  }
  #pragma unroll
  for (int m = 4; m < 64; m <<= 1) acc += __shfl_xor(acc, m, 64);
  __shared__ float wsum[4];
  if (lane == 0) wsum[t >> 6] = acc;
  __syncthreads();
  if (t == 0)
    atomicAdd(&ws[WS_CUT], wsum[0] + wsum[1] + wsum[2] + wsum[3]);
}

// ---------------------------------------------------------------------------
// Z = M @ W_proj + colsum(S) (x) b_proj
__global__ __launch_bounds__(256)
void k_z(const float* __restrict__ ws, const float* __restrict__ Wp,
         const float* __restrict__ bp, float* __restrict__ out) {
  const int r = blockIdx.x, t = threadIdx.x;
  const float* m = ws + WS_M + r * 256;
  float acc = ws[WS_CS + r] * bp[t];
  #pragma unroll 8
  for (int k = 0; k < 256; ++k) acc += m[k] * Wp[(size_t)k * 256 + t];
  out[OUT_Z + r * 256 + t] = acc;
}

// ---------------------------------------------------------------------------
// Shapley layer (mask=ones, n=30): h = relu((in + colsum(in)/30) @ W)
__global__ __launch_bounds__(256)
void k_shlayer(const float* __restrict__ in, const float* __restrict__ W,
               float* __restrict__ outp) {
  __shared__ float sh[256];
  const int r = blockIdx.x, t = threadIdx.x;
  float cs = 0.f;
  #pragma unroll
  for (int i = 0; i < C_CL; ++i) cs += in[i * 256 + t];
  sh[t] = in[r * 256 + t] + (1.f / 30.f) * cs;
  __syncthreads();
  float acc = 0.f;
  #pragma unroll 8
  for (int k = 0; k < 256; ++k) acc += sh[k] * W[(size_t)k * 256 + t];
  outp[r * 256 + t] = fmaxf(acc, 0.f);
}

// ---------------------------------------------------------------------------
// out = h2 @ W_out + b_out ; block 30: mincut + ortho scalars
__global__ __launch_bounds__(64)
void k_out(const float* __restrict__ ws, const float* __restrict__ Wo,
           const float* __restrict__ bo, float* __restrict__ out,
           const float vol) {
  const int r = blockIdx.x, t = threadIdx.x;
  if (r < C_CL) {
    const float* hrow = ws + WS_H2 + r * 256;
    float acc = bo[t];
    #pragma unroll 8
    for (int k = 0; k < 256; ++k) acc += hrow[k] * Wo[k * 64 + t];
    out[OUT_MAT + r * 64 + t] = acc;
  } else {
    float s = 0.f;
    for (int i = t; i < C_CL * C_CL; i += 64) {
      const float d = ws[WS_SS + i] - ((i / C_CL == i % C_CL) ? 1.f : 0.f);
      s += d * d;
    }
    #pragma unroll
    for (int m = 32; m >= 1; m >>= 1) s += __shfl_xor(s, m, 64);
    if (t == 0) {
      out[OUT_OR] = sqrtf(s);
      out[OUT_MC] = -ws[WS_CUT] / (vol + 1e-9f);
    }
  }
}

// ---------------------------------------------------------------------------
extern "C" void kernel_launch(void* const* d_in, const int* in_sizes, int n_in,
                              void* d_out, int out_size, void* d_ws, size_t ws_size,
                              hipStream_t stream) {
  (void)n_in; (void)out_size;
  const float* x  = (const float*)d_in[0];
  const int*   ei = (const int*)d_in[1];
  const float* Wa = (const float*)d_in[2];
  const float* ba = (const float*)d_in[3];
  const float* Wp = (const float*)d_in[4];
  const float* bp = (const float*)d_in[5];
  const float* W1 = (const float*)d_in[6];
  const float* W2 = (const float*)d_in[7];
  const float* Wo = (const float*)d_in[8];
  const float* bo = (const float*)d_in[9];
  float* out = (float*)d_out;
  float* ws  = (float*)d_ws;
  unsigned* S16 = (unsigned*)(ws + WS_S16);
  float* Q = ws + WS_Q;
  float* slabs = ws + WS_SLAB0;
  const int E = in_sizes[1] / 2;

  long avail = (long)(ws_size / 4) - WS_SLAB0;
  int R = (int)(avail / SLAB_STRIDE);
  if (R > MAX_R) R = MAX_R;
  if (R < 1) R = 1;

  k_prep<<<9, 256, 0, stream>>>(Wa, ws);
  k_node<<<1563, 256, 0, stream>>>(x, ws + WS_WT4, ba, out + OUT_S, S16);
  k_M2<<<R, 256, 0, stream>>>(x, out + OUT_S, slabs, R);
  k_reduce_a<<<dim3(34, 16), 256, 0, stream>>>(slabs, R, Q);
  k_reduce_b<<<34, 256, 0, stream>>>(Q, ws);
  k_edges<<<4096, 256, 0, stream>>>(ei, E, S16, ws);
  k_z<<<C_CL, 256, 0, stream>>>(ws, Wp, bp, out);
  k_shlayer<<<C_CL, 256, 0, stream>>>(out + OUT_Z, W1, ws + WS_H1);
  k_shlayer<<<C_CL, 256, 0, stream>>>(ws + WS_H1, W2, ws + WS_H2);
  k_out<<<C_CL + 1, 64, 0, stream>>>(ws, Wo, bo, out, (float)E);
}

// Round 7
// 422.511 us; speedup vs baseline: 1.9453x; 1.0430x over previous
//
#include <hip/hip_runtime.h>
#include <math.h>

typedef float f32x4 __attribute__((ext_vector_type(4)));

// Problem constants (from reference)
#define N_NODES 100000
#define C_CL 30
#define D_IN 256

// d_out float offsets: (out, mincut, ortho, Z, S) concatenated
#define OUT_MAT 0        // 30*64
#define OUT_MC 1920
#define OUT_OR 1921
#define OUT_Z 1922       // 30*256
#define OUT_S 9602       // N*30

// ws float offsets
#define WS_M 0           // 30*256  (M = S^T x)      [written by k_reduce_b]
#define WS_SS 7680       // 30*30
#define WS_CS 8580       // 30 (colsum S)
#define WS_CUT 8610      // 1  (zeroed by k_prep, atomic from k_edges)
#define WS_H1 8640       // 30*256
#define WS_H2 16320      // 30*256
#define WS_WT4 24000     // 64*32 float4 = 8192 floats (W padded to 32 cols)
#define WS_S8 32256      // u8 S table: 1563*64 rows * 8 dwords = 3.2 MB (L2-resident)
#define WS_Q 1632768     // stage-A partials: 16 * 8640 floats
#define Q_STRIDE 8640
#define WS_SLAB0 1771008 // per-block partial slabs start (floats)

// slab layout (floats, per block)
#define SLAB_SS 7680     // 4 w-partials * 900
#define SLAB_CS 11280    // 30
#define SLAB_STRIDE 11328
#define MAX_R 512

#define CHUNK 128
#define NCHUNK ((N_NODES + CHUNK - 1) / CHUNK)   // 782

// ---------------------------------------------------------------------------
// prep: build WT4p[k4][c] (c padded to 32, cols 30/31 = 0); zero WS_CUT
__global__ __launch_bounds__(256)
void k_prep(const float* __restrict__ Wa, float* __restrict__ ws) {
  const int b = blockIdx.x, t = threadIdx.x;
  if (b < 8) {
    const int g = b * 256 + t;          // 0..2047 = 64 k4 * 32 c
    const int k4 = g >> 5, c = g & 31;
    float4 v = make_float4(0.f, 0.f, 0.f, 0.f);
    if (c < C_CL) {
      v.x = Wa[(4 * k4 + 0) * C_CL + c];
      v.y = Wa[(4 * k4 + 1) * C_CL + c];
      v.z = Wa[(4 * k4 + 2) * C_CL + c];
      v.w = Wa[(4 * k4 + 3) * C_CL + c];
    }
    reinterpret_cast<float4*>(ws + WS_WT4)[g] = v;
  } else {
    if (t == 0) ws[WS_CUT] = 0.f;
  }
}

// ---------------------------------------------------------------------------
// k_node v4: block = 256 threads = 4 waves over the SAME 64 nodes.
// Wave cg computes clusters [cg*8, cg*8+8): acc[8] keeps VGPRs low.
// All 4 waves read the same x lines (plain loads -> L1/L2 dedup).
// W loads wave-uniform via readfirstlane -> scalar path. Softmax via LDS.
// Outputs: packed fp32 S + u8 fixed-point S (32 B/row, for k_edges).
__global__ __launch_bounds__(256, 4)
void k_node(const float* __restrict__ x, const float* __restrict__ wt4f,
            const float* __restrict__ ba, float* __restrict__ S_out,
            unsigned* __restrict__ S8) {
  __shared__ float lg[64][33];
  const int t = threadIdx.x;
  const int lane = t & 63;
  const int cg = __builtin_amdgcn_readfirstlane(t >> 6);   // wave-uniform 0..3
  const int node = blockIdx.x * 64 + lane;
  const bool valid = (node < N_NODES);
  const int node_c = valid ? node : (N_NODES - 1);
  const f32x4* __restrict__ xr =
      reinterpret_cast<const f32x4*>(x) + (size_t)node_c * 64;
  const float4* __restrict__ wt4 = reinterpret_cast<const float4*>(wt4f);

  float acc[8];
  #pragma unroll
  for (int j = 0; j < 8; ++j) acc[j] = 0.f;

  #pragma unroll 8
  for (int k4 = 0; k4 < 64; ++k4) {
    const f32x4 xv = xr[k4];                       // cached: shared by 4 waves
    #pragma unroll
    for (int j = 0; j < 8; ++j) {
      const float4 wv = wt4[k4 * 32 + cg * 8 + j]; // scalar loads
      acc[j] += xv.x * wv.x + xv.y * wv.y + xv.z * wv.z + xv.w * wv.w;
    }
  }
  #pragma unroll
  for (int j = 0; j < 8; ++j) lg[lane][cg * 8 + j] = acc[j];
  __syncthreads();

  // ---- softmax by wave 0 (reads combined logits from LDS) ----
  if (t < 64) {
    if (valid) {
      float v[C_CL];
      float mx = -3.0e38f;
      #pragma unroll
      for (int c = 0; c < C_CL; ++c) {
        v[c] = lg[t][c] + ba[c];
        mx = fmaxf(mx, v[c]);
      }
      float sm = 0.f;
      #pragma unroll
      for (int c = 0; c < C_CL; ++c) { v[c] = __expf(v[c] - mx); sm += v[c]; }
      const float r = 1.f / sm;
      #pragma unroll
      for (int c = 0; c < C_CL; ++c) lg[t][c] = v[c] * r;
    } else {
      #pragma unroll
      for (int c = 0; c < C_CL; ++c) lg[t][c] = 0.f;
    }
    lg[t][30] = 0.f; lg[t][31] = 0.f;
  }
  __syncthreads();

  // ---- outputs (256 threads) ----
  // packed fp32 S: 64 rows * 30 floats = 1920
  const int gbase = blockIdx.x * 1920;
  #pragma unroll
  for (int i = 0; i < 8; ++i) {
    const unsigned idx = i * 256 + t;
    if (idx < 1920u) {
      const unsigned n = idx / 30u, c = idx - 30u * n;
      const int g = gbase + (int)idx;
      if (g < N_NODES * C_CL) S_out[g] = lg[n][c];
    }
  }
  // u8 S: 64 rows * 8 dwords = 512 (row = half a 64B line; table 3.2 MB)
  const unsigned sbase = blockIdx.x * 512;
  #pragma unroll
  for (int i = 0; i < 2; ++i) {
    const unsigned idx = i * 256 + t;            // 0..511
    const unsigned n = idx >> 3, j = idx & 7;
    const unsigned b0 = (unsigned)(lg[n][j * 4 + 0] * 255.f + 0.5f);
    const unsigned b1 = (unsigned)(lg[n][j * 4 + 1] * 255.f + 0.5f);
    const unsigned b2 = (unsigned)(lg[n][j * 4 + 2] * 255.f + 0.5f);
    const unsigned b3 = (unsigned)(lg[n][j * 4 + 3] * 255.f + 0.5f);
    S8[sbase + idx] = b0 | (b1 << 8) | (b2 << 16) | (b3 << 24);
  }
}

// ---------------------------------------------------------------------------
// M = S^T x (+ SS = S^T S, colsum). Grid-stride over 128-node chunks,
// persistent register accumulators, per-block slab output (no atomics).
__global__ __launch_bounds__(256, 2)
void k_M2(const float* __restrict__ x, const float* __restrict__ Sp,
          float* __restrict__ slabs, const int R) {
  __shared__ float sraw[8192];                 // 32 KB, dual-use
  float (*sm)[32] = reinterpret_cast<float (*)[32]>(sraw);
  const int t = threadIdx.x;
  const int h = t >> 7, sub = (t >> 6) & 1, lc = t & 63;  // M layout
  const int i4 = (t >> 3) & 7, j4 = t & 7, w = t >> 6;    // SS layout
  const f32x4* __restrict__ x4 = reinterpret_cast<const f32x4*>(x);

  float a[16][4];
  #pragma unroll
  for (int j = 0; j < 16; ++j) { a[j][0] = 0.f; a[j][1] = 0.f; a[j][2] = 0.f; a[j][3] = 0.f; }
  float ssq[16];
  #pragma unroll
  for (int j = 0; j < 16; ++j) ssq[j] = 0.f;
  float cs = 0.f;

  for (int chunk = blockIdx.x; chunk < NCHUNK; chunk += R) {
    const int node0 = chunk * CHUNK;
    const int rows_valid = N_NODES - node0;
    __syncthreads();
    #pragma unroll
    for (int i = 0; i < 15; ++i) {
      const int idx = i * 256 + t;
      const int n = idx / 30, c = idx - 30 * n;
      const int g = node0 * C_CL + idx;
      sm[n][c] = (g < N_NODES * C_CL) ? Sp[g] : 0.f;
    }
    sm[t & 127][30 + (t >> 7)] = 0.f;
    __syncthreads();

    if (rows_valid >= CHUNK) {
      #pragma unroll 4
      for (int n = 0; n < 64; ++n) {
        const int nn = sub * 64 + n;
        const f32x4 xv = __builtin_nontemporal_load(&x4[(size_t)(node0 + nn) * 64 + lc]);
        const float4 s0 = *reinterpret_cast<const float4*>(&sm[nn][h * 16 + 0]);
        const float4 s1 = *reinterpret_cast<const float4*>(&sm[nn][h * 16 + 4]);
        const float4 s2 = *reinterpret_cast<const float4*>(&sm[nn][h * 16 + 8]);
        const float4 s3 = *reinterpret_cast<const float4*>(&sm[nn][h * 16 + 12]);
        const float sv[16] = {s0.x, s0.y, s0.z, s0.w, s1.x, s1.y, s1.z, s1.w,
                              s2.x, s2.y, s2.z, s2.w, s3.x, s3.y, s3.z, s3.w};
        #pragma unroll
        for (int j = 0; j < 16; ++j) {
          a[j][0] += sv[j] * xv.x; a[j][1] += sv[j] * xv.y;
          a[j][2] += sv[j] * xv.z; a[j][3] += sv[j] * xv.w;
        }
      }
    } else {
      for (int n = 0; n < 64; ++n) {
        const int nn = sub * 64 + n;
        f32x4 xv = (f32x4)0.f;
        if (nn < rows_valid) xv = x4[(size_t)(node0 + nn) * 64 + lc];
        const float4 s0 = *reinterpret_cast<const float4*>(&sm[nn][h * 16 + 0]);
        const float4 s1 = *reinterpret_cast<const float4*>(&sm[nn][h * 16 + 4]);
        const float4 s2 = *reinterpret_cast<const float4*>(&sm[nn][h * 16 + 8]);
        const float4 s3 = *reinterpret_cast<const float4*>(&sm[nn][h * 16 + 12]);
        const float sv[16] = {s0.x, s0.y, s0.z, s0.w, s1.x, s1.y, s1.z, s1.w,
                              s2.x, s2.y, s2.z, s2.w, s3.x, s3.y, s3.z, s3.w};
        #pragma unroll
        for (int j = 0; j < 16; ++j) {
          a[j][0] += sv[j] * xv.x; a[j][1] += sv[j] * xv.y;
          a[j][2] += sv[j] * xv.z; a[j][3] += sv[j] * xv.w;
        }
      }
    }

    #pragma unroll 4
    for (int n = 0; n < 32; ++n) {
      const int nn = w * 32 + n;
      const float4 av = *reinterpret_cast<const float4*>(&sm[nn][i4 * 4]);
      const float4 bv = *reinterpret_cast<const float4*>(&sm[nn][j4 * 4]);
      const float af[4] = {av.x, av.y, av.z, av.w};
      const float bf[4] = {bv.x, bv.y, bv.z, bv.w};
      #pragma unroll
      for (int ii = 0; ii < 4; ++ii)
        #pragma unroll
        for (int jj = 0; jj < 4; ++jj) ssq[ii * 4 + jj] += af[ii] * bf[jj];
    }
    if (t < C_CL) {
      #pragma unroll 4
      for (int n = 0; n < CHUNK; ++n) cs += sm[n][t];
    }
  }

  // ---- flush to private slab (plain stores; zero contention) ----
  float* __restrict__ slab = slabs + (size_t)blockIdx.x * SLAB_STRIDE;
  __syncthreads();
  if (sub == 1) {
    #pragma unroll
    for (int j = 0; j < 16; ++j) {
      const int c = h * 16 + j;
      if (c < C_CL) {
        #pragma unroll
        for (int q = 0; q < 4; ++q) sraw[c * 256 + lc * 4 + q] = a[j][q];
      }
    }
  }
  __syncthreads();
  if (sub == 0) {
    #pragma unroll
    for (int j = 0; j < 16; ++j) {
      const int c = h * 16 + j;
      if (c < C_CL) {
        #pragma unroll
        for (int q = 0; q < 4; ++q)
          slab[c * 256 + lc * 4 + q] = a[j][q] + sraw[c * 256 + lc * 4 + q];
      }
    }
  }
  #pragma unroll
  for (int ii = 0; ii < 4; ++ii) {
    #pragma unroll
    for (int jj = 0; jj < 4; ++jj) {
      const int gi = i4 * 4 + ii, gj = j4 * 4 + jj;
      if (gi < C_CL && gj < C_CL)
        slab[SLAB_SS + w * 900 + gi * C_CL + gj] = ssq[ii * 4 + jj];
    }
  }
  if (t < C_CL) slab[SLAB_CS + t] = cs;
}

// ---------------------------------------------------------------------------
// Stage A: 34 x 16 blocks; group g sums its ~R/16 slabs with batched loads.
__global__ __launch_bounds__(256)
void k_reduce_a(const float* __restrict__ slabs, const int R,
                float* __restrict__ Q) {
  const int i = blockIdx.x * 256 + threadIdx.x;
  const int g = blockIdx.y;
  if (i >= 8610) return;
  const int per = (R + 15) >> 4;
  const int r0 = g * per;
  const int r1 = min(r0 + per, R);
  size_t off;
  bool is_ss = false;
  if (i < 7680) off = (size_t)i;
  else if (i < 8580) { off = SLAB_SS + (i - 7680); is_ss = true; }
  else off = SLAB_CS + (i - 8580);

  float s = 0.f;
  if (!is_ss) {
    int r = r0;
    for (; r + 8 <= r1; r += 8) {
      const float* p = slabs + (size_t)r * SLAB_STRIDE + off;
      const float v0 = p[0];
      const float v1 = p[1 * SLAB_STRIDE];
      const float v2 = p[2 * SLAB_STRIDE];
      const float v3 = p[3 * SLAB_STRIDE];
      const float v4 = p[4 * SLAB_STRIDE];
      const float v5 = p[5 * SLAB_STRIDE];
      const float v6 = p[6 * SLAB_STRIDE];
      const float v7 = p[7 * SLAB_STRIDE];
      s += ((v0 + v1) + (v2 + v3)) + ((v4 + v5) + (v6 + v7));
    }
    for (; r < r1; ++r) s += slabs[(size_t)r * SLAB_STRIDE + off];
  } else {
    int r = r0;
    for (; r + 2 <= r1; r += 2) {
      const float* p0 = slabs + (size_t)r * SLAB_STRIDE + off;
      const float* p1 = p0 + SLAB_STRIDE;
      s += ((p0[0] + p0[900]) + (p0[1800] + p0[2700]))
         + ((p1[0] + p1[900]) + (p1[1800] + p1[2700]));
    }
    if (r < r1) {
      const float* p = slabs + (size_t)r * SLAB_STRIDE + off;
      s += (p[0] + p[900]) + (p[1800] + p[2700]);
    }
  }
  Q[(size_t)g * Q_STRIDE + i] = s;
}

// Stage B: ws[i] = sum_g Q[g][i], 16 unrolled independent loads.
__global__ __launch_bounds__(256)
void k_reduce_b(const float* __restrict__ Q, float* __restrict__ ws) {
  const int i = blockIdx.x * 256 + threadIdx.x;
  if (i >= 8610) return;
  float s = 0.f;
  #pragma unroll
  for (int g = 0; g < 16; ++g) s += Q[(size_t)g * Q_STRIDE + i];
  ws[i] = s;
}

// ---------------------------------------------------------------------------
// cut = sum_e dot(S[r], S[c]); u8 rows (32 B, table 3.2 MB -> L2-resident).
// One edge per thread; exact integer dot (30 u8*u8 terms), scale once.
__device__ __forceinline__ int dd(unsigned a, unsigned b, int acc) {
  acc += (int)((a & 0xffu) * (b & 0xffu));
  acc += (int)(((a >> 8) & 0xffu) * ((b >> 8) & 0xffu));
  acc += (int)(((a >> 16) & 0xffu) * ((b >> 16) & 0xffu));
  acc += (int)((a >> 24) * (b >> 24));
  return acc;
}

__global__ __launch_bounds__(256)
void k_edges(const int* __restrict__ ei, const int E,
             const unsigned* __restrict__ S8, float* __restrict__ ws) {
  const int t = threadIdx.x;
  const int tid = blockIdx.x * 256 + t;
  const int* __restrict__ row = ei;
  const int* __restrict__ col = ei + E;
  float acc = 0.f;
  for (int e = tid; e < E; e += gridDim.x * 256) {
    const int r = row[e], c = col[e];
    const uint4* pr = reinterpret_cast<const uint4*>(S8 + (size_t)r * 8);
    const uint4* pc = reinterpret_cast<const uint4*>(S8 + (size_t)c * 8);
    const uint4 a0 = pr[0], a1 = pr[1];
    const uint4 b0 = pc[0], b1 = pc[1];
    int s = 0;
    s = dd(a0.x, b0.x, s); s = dd(a0.y, b0.y, s);
    s = dd(a0.z, b0.z, s); s = dd(a0.w, b0.w, s);
    s = dd(a1.x, b1.x, s); s = dd(a1.y, b1.y, s);
    s = dd(a1.z, b1.z, s); s = dd(a1.w, b1.w, s);
    acc += (float)s;
  }
  acc *= (1.f / 65025.f);     // (1/255)^2
  #pragma unroll
  for (int m = 1; m < 64; m <<= 1) acc += __shfl_xor(acc, m, 64);
  __shared__ float wsum[4];
  if ((t & 63) == 0) wsum[t >> 6] = acc;
  __syncthreads();
  if (t == 0)
    atomicAdd(&ws[WS_CUT], wsum[0] + wsum[1] + wsum[2] + wsum[3]);
}

// ---------------------------------------------------------------------------
// Z = M @ W_proj + colsum(S) (x) b_proj
__global__ __launch_bounds__(256)
void k_z(const float* __restrict__ ws, const float* __restrict__ Wp,
         const float* __restrict__ bp, float* __restrict__ out) {
  const int r = blockIdx.x, t = threadIdx.x;
  const float* m = ws + WS_M + r * 256;
  float acc = ws[WS_CS + r] * bp[t];
  #pragma unroll 8
  for (int k = 0; k < 256; ++k) acc += m[k] * Wp[(size_t)k * 256 + t];
  out[OUT_Z + r * 256 + t] = acc;
}

// ---------------------------------------------------------------------------
// Shapley layer (mask=ones, n=30): h = relu((in + colsum(in)/30) @ W)
__global__ __launch_bounds__(256)
void k_shlayer(const float* __restrict__ in, const float* __restrict__ W,
               float* __restrict__ outp) {
  __shared__ float sh[256];
  const int r = blockIdx.x, t = threadIdx.x;
  float cs = 0.f;
  #pragma unroll
  for (int i = 0; i < C_CL; ++i) cs += in[i * 256 + t];
  sh[t] = in[r * 256 + t] + (1.f / 30.f) * cs;
  __syncthreads();
  float acc = 0.f;
  #pragma unroll 8
  for (int k = 0; k < 256; ++k) acc += sh[k] * W[(size_t)k * 256 + t];
  outp[r * 256 + t] = fmaxf(acc, 0.f);
}

// ---------------------------------------------------------------------------
// out = h2 @ W_out + b_out ; block 30: mincut + ortho scalars
__global__ __launch_bounds__(64)
void k_out(const float* __restrict__ ws, const float* __restrict__ Wo,
           const float* __restrict__ bo, float* __restrict__ out,
           const float vol) {
  const int r = blockIdx.x, t = threadIdx.x;
  if (r < C_CL) {
    const float* hrow = ws + WS_H2 + r * 256;
    float acc = bo[t];
    #pragma unroll 8
    for (int k = 0; k < 256; ++k) acc += hrow[k] * Wo[k * 64 + t];
    out[OUT_MAT + r * 64 + t] = acc;
  } else {
    float s = 0.f;
    for (int i = t; i < C_CL * C_CL; i += 64) {
      const float d = ws[WS_SS + i] - ((i / C_CL == i % C_CL) ? 1.f : 0.f);
      s += d * d;
    }
    #pragma unroll
    for (int m = 32; m >= 1; m >>= 1) s += __shfl_xor(s, m, 64);
    if (t == 0) {
      out[OUT_OR] = sqrtf(s);
      out[OUT_MC] = -ws[WS_CUT] / (vol + 1e-9f);
    }
  }
}

// ---------------------------------------------------------------------------
extern "C" void kernel_launch(void* const* d_in, const int* in_sizes, int n_in,
                              void* d_out, int out_size, void* d_ws, size_t ws_size,
                              hipStream_t stream) {
  (void)n_in; (void)out_size;
  const float* x  = (const float*)d_in[0];
  const int*   ei = (const int*)d_in[1];
  const float* Wa = (const float*)d_in[2];
  const float* ba = (const float*)d_in[3];
  const float* Wp = (const float*)d_in[4];
  const float* bp = (const float*)d_in[5];
  const float* W1 = (const float*)d_in[6];
  const float* W2 = (const float*)d_in[7];
  const float* Wo = (const float*)d_in[8];
  const float* bo = (const float*)d_in[9];
  float* out = (float*)d_out;
  float* ws  = (float*)d_ws;
  unsigned* S8 = (unsigned*)(ws + WS_S8);
  float* Q = ws + WS_Q;
  float* slabs = ws + WS_SLAB0;
  const int E = in_sizes[1] / 2;

  long avail = (long)(ws_size / 4) - WS_SLAB0;
  int R = (int)(avail / SLAB_STRIDE);
  if (R > MAX_R) R = MAX_R;
  if (R < 1) R = 1;

  k_prep<<<9, 256, 0, stream>>>(Wa, ws);
  k_node<<<1563, 256, 0, stream>>>(x, ws + WS_WT4, ba, out + OUT_S, S8);
  k_M2<<<R, 256, 0, stream>>>(x, out + OUT_S, slabs, R);
  k_reduce_a<<<dim3(34, 16), 256, 0, stream>>>(slabs, R, Q);
  k_reduce_b<<<34, 256, 0, stream>>>(Q, ws);
  k_edges<<<4096, 256, 0, stream>>>(ei, E, S8, ws);
  k_z<<<C_CL, 256, 0, stream>>>(ws, Wp, bp, out);
  k_shlayer<<<C_CL, 256, 0, stream>>>(out + OUT_Z, W1, ws + WS_H1);
  k_shlayer<<<C_CL, 256, 0, stream>>>(ws + WS_H1, W2, ws + WS_H2);
  k_out<<<C_CL + 1, 64, 0, stream>>>(ws, Wo, bo, out, (float)E);
}